// Round 11
// baseline (15008.617 us; speedup 1.0000x reference)
//
#include <hip/hip_runtime.h>
#include <hip/hip_bf16.h>
#include <hip/hip_fp16.h>

#define NB 8
#define NP 8192
#define NC 64
#define NM 2048
#define NK 32
#define RAD2 0.04f

typedef unsigned int u32;
typedef unsigned long long u64;
typedef _Float16 f16x8 __attribute__((ext_vector_type(8)));
typedef float f32x4 __attribute__((ext_vector_type(4)));

// exact reference arithmetic: ((dx*dx + dy*dy) + dz*dz), no FMA contraction
__device__ __forceinline__ float d2e(float ax, float ay, float az,
                                     float bx, float by, float bz) {
    float dx = __fsub_rn(ax, bx), dy = __fsub_rn(ay, by), dz = __fsub_rn(az, bz);
    return __fadd_rn(__fadd_rn(__fmul_rn(dx, dx), __fmul_rn(dy, dy)), __fmul_rn(dz, dz));
}

__device__ __forceinline__ int spread3(int v) {
    return (v & 1) | ((v & 2) << 2) | ((v & 4) << 4);
}

// one DPP combine level of u64 max (keys unique -> strict > is exact)
#define RED64(CTRL) do {                                                              \
    u32 hi_ = (u32)(k >> 32), lo_ = (u32)k;                                           \
    u32 h2_ = (u32)__builtin_amdgcn_update_dpp((int)hi_, (int)hi_, (CTRL), 0xF, 0xF, false); \
    u32 l2_ = (u32)__builtin_amdgcn_update_dpp((int)lo_, (int)lo_, (CTRL), 0xF, 0xF, false); \
    u64 o_ = ((u64)h2_ << 32) | l2_;                                                  \
    if (o_ > k) k = o_;                                                               \
} while (0)

// ---------------- Kernel 1: farthest point sampling (1 block per cloud) ----
// 256-thread setup (Morton sort, interleaved layout, cell metadata), then a
// SINGLE WAVE runs the greedy loop barrier-free. Cell bbox/max live in LDS
// (NOT registers -- r9's register arrays spilled to scratch). Per lane:
// 128 pts = 8 cells x 16. LDS = exactly 160 KiB with setup-time overlays.
__global__ __launch_bounds__(256, 1) void fps_kernel(const float* __restrict__ pos,
                                                     float* __restrict__ pos_s) {
    __shared__ float4 sp4[NP];               // 128K: x,y,z, w = mind bits (interleaved)
    __shared__ unsigned short lsid[NP];      // 16K: original id per sorted slot
    __shared__ float cbb[6][512];            // 12K: cell bbox SoA (lo x,hi x,lo y,hi y,lo z,hi z)
    __shared__ u64 cmaxl[512];               // 4K: per-cell max key
    // setup-time overlays (cbb written only after these are dead):
    u32* hist = (u32*)&cbb[0][0];            // 512 u32
    u32* cursor = (u32*)&cbb[2][0];          // 512 u32
    float* s0sh = &cbb[4][0];                // 3 floats

    const int b = blockIdx.x;
    const int tid = threadIdx.x;
    const float* pb = pos + (size_t)b * (NP * 3);

    hist[tid] = 0; hist[tid + 256] = 0;
    if (tid == 0) { s0sh[0] = pb[0]; s0sh[1] = pb[1]; s0sh[2] = pb[2]; }
    __syncthreads();

    // ---- phase A: morton histogram (4 chunks x 8 contiguous pts) ----
    for (int ch = 0; ch < 4; ++ch) {
        float f[24];
        const float4* src = (const float4*)(pb + (size_t)(tid * 32 + ch * 8) * 3);
#pragma unroll
        for (int v = 0; v < 6; ++v) *(float4*)&f[v * 4] = src[v];
#pragma unroll
        for (int j = 0; j < 8; ++j) {
            int qx = min(7, max(0, (int)(f[3 * j] * 8.0f)));
            int qy = min(7, max(0, (int)(f[3 * j + 1] * 8.0f)));
            int qz = min(7, max(0, (int)(f[3 * j + 2] * 8.0f)));
            int key = (spread3(qx) << 2) | (spread3(qy) << 1) | spread3(qz);
            atomicAdd(&hist[key], 1);
        }
    }
    __syncthreads();
    // inclusive scan over 512 bins with 256 threads (2 bins/thread)
    for (int off = 1; off < 512; off <<= 1) {
        u32 a0 = (tid >= off) ? hist[tid - off] : 0;
        u32 a1 = hist[tid + 256 - off];
        __syncthreads();
        hist[tid] += a0; hist[tid + 256] += a1;
        __syncthreads();
    }
    cursor[tid] = (tid == 0) ? 0u : hist[tid - 1];
    cursor[tid + 256] = hist[tid + 255];
    __syncthreads();

    const float s0x = s0sh[0], s0y = s0sh[1], s0z = s0sh[2];
    float* outp = pos_s + (size_t)b * (NM * 3);
    if (tid == 0) { outp[0] = s0x; outp[1] = s0y; outp[2] = s0z; }
    // ---- phase B: scatter into morton order (interleaved) + mind init ----
    for (int ch = 0; ch < 4; ++ch) {
        float f[24];
        const float4* src = (const float4*)(pb + (size_t)(tid * 32 + ch * 8) * 3);
#pragma unroll
        for (int v = 0; v < 6; ++v) *(float4*)&f[v * 4] = src[v];
#pragma unroll
        for (int j = 0; j < 8; ++j) {
            float x = f[3 * j], y = f[3 * j + 1], z = f[3 * j + 2];
            int qx = min(7, max(0, (int)(x * 8.0f)));
            int qy = min(7, max(0, (int)(y * 8.0f)));
            int qz = min(7, max(0, (int)(z * 8.0f)));
            int key = (spread3(qx) << 2) | (spread3(qy) << 1) | spread3(qz);
            int dst = (int)atomicAdd(&cursor[key], 1);
            int m = ((dst & 127) << 6) | (dst >> 7);   // interleave: j*64+lane
            float mind = d2e(x, y, z, s0x, s0y, s0z);
            sp4[m] = make_float4(x, y, z, mind);       // w holds mind bits (d2>=0)
            lsid[m] = (unsigned short)(tid * 32 + ch * 8 + j);
        }
    }
    __syncthreads();

    // ---- phase C: cell metadata (512 cells, 2 per thread) ----
    // cell = lane*8 + c  owns sorted range lane*128 + c*16 + [0,16)
#pragma unroll
    for (int half = 0; half < 2; ++half) {
        int cell = tid + half * 256;
        int L = cell >> 3, c = cell & 7;
        float lx = 1e30f, hx = -1e30f, ly = 1e30f, hy = -1e30f, lz = 1e30f, hz = -1e30f;
        u64 cm = 0;
        for (int i = 0; i < 16; ++i) {
            int m = ((c * 16 + i) << 6) | L;
            float4 v = sp4[m];
            u32 sid = (u32)lsid[m];
            u64 kk = ((u64)__float_as_uint(v.w) << 32)
                   | (((8191u - sid) << 13) | (u32)(L * 128 + c * 16 + i));
            cm = (kk > cm) ? kk : cm;
            lx = fminf(lx, v.x); hx = fmaxf(hx, v.x);
            ly = fminf(ly, v.y); hy = fmaxf(hy, v.y);
            lz = fminf(lz, v.z); hz = fmaxf(hz, v.z);
        }
        // overwrites hist/cursor/s0 region -- all dead by now
        __syncthreads();   // ensure overlay reads done before first overwrite
        cbb[0][cell] = lx; cbb[1][cell] = hx;
        cbb[2][cell] = ly; cbb[3][cell] = hy;
        cbb[4][cell] = lz; cbb[5][cell] = hz;
        cmaxl[cell] = cm;
    }
    __syncthreads();
    if (tid >= 64) return;   // waves 1-3 done; wave 0 runs barrier-free

    const int lane = tid;
    // lane bbox + lane max from my 8 cells
    float llox = 1e30f, lhix = -1e30f, lloy = 1e30f, lhiy = -1e30f;
    float lloz = 1e30f, lhiz = -1e30f;
    u64 lmax = 0;
#pragma unroll
    for (int c = 0; c < 8; ++c) {
        int cell = lane * 8 + c;
        llox = fminf(llox, cbb[0][cell]); lhix = fmaxf(lhix, cbb[1][cell]);
        lloy = fminf(lloy, cbb[2][cell]); lhiy = fmaxf(lhiy, cbb[3][cell]);
        lloz = fminf(lloz, cbb[4][cell]); lhiz = fmaxf(lhiz, cbb[5][cell]);
        u64 cm = cmaxl[cell];
        lmax = (cm > lmax) ? cm : lmax;
    }

    // ---- main loop: single wave, no barriers, no atomics ----
    for (int t = 1; t < NM; ++t) {
        u64 k = lmax;
        RED64(0x111); RED64(0x112); RED64(0x114);
        RED64(0x118); RED64(0x142); RED64(0x143);
        const u32 glo = (u32)__builtin_amdgcn_readlane((int)(u32)k, 63);
        const int srt = (int)(glo & 0x1FFFu);
        const int m = ((srt & 127) << 6) | (srt >> 7);
        const float4 sv = sp4[m];                       // uniform broadcast read
        if (lane == 0) { outp[3 * t] = sv.x; outp[3 * t + 1] = sv.y; outp[3 * t + 2] = sv.z; }
        // lane-level certified skip over my 128 points
        float gx = fmaxf(fmaxf(llox - sv.x, sv.x - lhix), 0.0f);
        float gy = fmaxf(fmaxf(lloy - sv.y, sv.y - lhiy), 0.0f);
        float gz = fmaxf(fmaxf(lloz - sv.z, sv.z - lhiz), 0.0f);
        float bnd = gx * gx + gy * gy + gz * gz;
        if (bnd * 0.999999f < __uint_as_float((u32)(lmax >> 32))) {
            u64 nl = 0;
            for (int c = 0; c < 8; ++c) {
                int cell = lane * 8 + c;
                u64 cm = cmaxl[cell];
                float cgx = fmaxf(fmaxf(cbb[0][cell] - sv.x, sv.x - cbb[1][cell]), 0.0f);
                float cgy = fmaxf(fmaxf(cbb[2][cell] - sv.y, sv.y - cbb[3][cell]), 0.0f);
                float cgz = fmaxf(fmaxf(cbb[4][cell] - sv.z, sv.z - cbb[5][cell]), 0.0f);
                float cbnd = cgx * cgx + cgy * cgy + cgz * cgz;
                if (cbnd * 0.999999f < __uint_as_float((u32)(cm >> 32))) {
                    cm = 0;
#pragma unroll
                    for (int i = 0; i < 16; ++i) {
                        int m2 = ((c * 16 + i) << 6) | lane;
                        float4 v = sp4[m2];
                        float d = d2e(v.x, v.y, v.z, sv.x, sv.y, sv.z);
                        u32 nmi = min(__float_as_uint(v.w), __float_as_uint(d));
                        ((float*)&sp4[m2])[3] = __uint_as_float(nmi);
                        u32 sid = (u32)lsid[m2];
                        u64 kk = ((u64)nmi << 32)
                               | (((8191u - sid) << 13) | (u32)(lane * 128 + c * 16 + i));
                        cm = (kk > cm) ? kk : cm;
                    }
                    cmaxl[cell] = cm;
                }
                nl = (cm > nl) ? cm : nl;
            }
            lmax = nl;
        }
    }
}

// ---------------- Kernel 2: radius-limited 32-NN (8 queries per block) -----
#define GQ 8
#define CAP 768
__global__ __launch_bounds__(256, 1) void knn_kernel(const float* __restrict__ pos,
                                                     const float* __restrict__ pos_s,
                                                     int* __restrict__ nbr) {
    __shared__ u64 keys[GQ][CAP];
    __shared__ int cnt[GQ];
    const int qbase = blockIdx.x * GQ;
    const int b = qbase >> 11;
    const int tid = threadIdx.x;
    if (tid < GQ) cnt[tid] = 0;
    for (int i = tid; i < GQ * NK; i += 256) nbr[qbase * NK + i] = -1;

    float qx[GQ], qy[GQ], qz[GQ];
#pragma unroll
    for (int q = 0; q < GQ; ++q) {
        qx[q] = pos_s[(qbase + q) * 3];
        qy[q] = pos_s[(qbase + q) * 3 + 1];
        qz[q] = pos_s[(qbase + q) * 3 + 2];
    }
    __syncthreads();

    const float* pb = pos + (size_t)b * (NP * 3);
    for (int i = 0; i < NP / 256; ++i) {
        int p = tid + (i << 8);
        float x = pb[3 * p], y = pb[3 * p + 1], z = pb[3 * p + 2];
#pragma unroll
        for (int q = 0; q < GQ; ++q) {
            float d = d2e(x, y, z, qx[q], qy[q], qz[q]);
            if (d <= RAD2) {
                int slot = atomicAdd(&cnt[q], 1);
                if (slot < CAP) keys[q][slot] = ((u64)__float_as_uint(d) << 32) | (u32)p;
            }
        }
    }
    __syncthreads();

    // exact rank selection: keys are unique (idx in low bits) -> stable top-k
    for (int q = 0; q < GQ; ++q) {
        int c = min(cnt[q], CAP);
        for (int j = tid; j < c; j += 256) {
            u64 key = keys[q][j];
            int rank = 0;
            for (int t2 = 0; t2 < c; ++t2) rank += (keys[q][t2] < key) ? 1 : 0;
            if (rank < NK) nbr[(qbase + q) * NK + rank] = (int)(u32)(key & 0xFFFFFFFFull);
        }
    }
}

// ---------------- Kernel 3: gather + MLP (fp16 MFMA) + masked max-pool -----
#define FPAD 104
#define HPAD 72
#define TG 8
__global__ __launch_bounds__(512, 1) void mlp_kernel(
    const float* __restrict__ x, const float* __restrict__ pos,
    const float* __restrict__ W0, const float* __restrict__ b0,
    const float* __restrict__ W1, const float* __restrict__ b1,
    const float* __restrict__ W2, const float* __restrict__ b2,
    const float* __restrict__ pos_s, const int* __restrict__ nbr,
    float* __restrict__ x1) {
    __shared__ _Float16 feat[256 * FPAD];   // reused as h2[256][HPAD] after GEMM1
    __shared__ _Float16 h1[256 * HPAD];
    __shared__ _Float16 wt0[64 * FPAD];
    __shared__ _Float16 wt1[64 * HPAD];
    __shared__ _Float16 wt2[128 * HPAD];
    __shared__ float bias0[64], bias1[64], bias2[128];
    __shared__ int vld[256];

    const int tid = threadIdx.x;
    const int g0 = blockIdx.x * TG;
    const int b = g0 >> 11;

    // stage weights transposed: wt[c][j] = W[j][c], zero-padded in K
    for (int idx = tid; idx < 64 * FPAD; idx += 512) {
        int c2 = idx / FPAD, j = idx - c2 * FPAD;
        wt0[idx] = (_Float16)((j < 67) ? W0[j * 64 + c2] : 0.0f);
    }
    for (int idx = tid; idx < 64 * HPAD; idx += 512) {
        int c2 = idx / HPAD, j = idx - c2 * HPAD;
        wt1[idx] = (_Float16)((j < 64) ? W1[j * 64 + c2] : 0.0f);
    }
    for (int idx = tid; idx < 128 * HPAD; idx += 512) {
        int c2 = idx / HPAD, j = idx - c2 * HPAD;
        wt2[idx] = (_Float16)((j < 64) ? W2[j * 128 + c2] : 0.0f);
    }
    if (tid < 64) { bias0[tid] = b0[tid]; bias1[tid] = b1[tid]; }
    else if (tid < 192) bias2[tid - 64] = b2[tid - 64];

    // gather features: 2 threads per row, rows = (group, k)
    {
        int r = tid >> 1, half = tid & 1;
        int g = g0 + (r >> 5), k = r & 31;
        int nid = nbr[g * NK + k];
        int nid2 = nid < 0 ? 0 : nid;
        const float* xr = x + ((size_t)b * NP + nid2) * NC + half * 32;
        _Float16* dst = &feat[r * FPAD + half * 32];
#pragma unroll
        for (int i = 0; i < 8; ++i) {
            float4 v = *(const float4*)(xr + i * 4);
            dst[i * 4 + 0] = (_Float16)v.x; dst[i * 4 + 1] = (_Float16)v.y;
            dst[i * 4 + 2] = (_Float16)v.z; dst[i * 4 + 3] = (_Float16)v.w;
        }
        if (half) {
            const float* pj = pos + ((size_t)b * NP + nid2) * 3;
            const float* ps = pos_s + (size_t)g * 3;
            feat[r * FPAD + 64] = (_Float16)(pj[0] - ps[0]);
            feat[r * FPAD + 65] = (_Float16)(pj[1] - ps[1]);
            feat[r * FPAD + 66] = (_Float16)(pj[2] - ps[2]);
#pragma unroll
            for (int j = 67; j < 96; ++j) feat[r * FPAD + j] = (_Float16)0.0f;
        } else {
            vld[r] = (nid >= 0) ? 1 : 0;
        }
    }
    __syncthreads();

    const int lane = tid & 63, w = tid >> 6;
    const int rb = w * 32;          // this wave owns one (b,m) group = 32 rows
    const int ar = lane & 15;
    const int kg = lane >> 4;

    // GEMM1: feat[256x96] x W0 -> h1[256x64], relu
    {
        f32x4 acc[2][4] = {};
#pragma unroll
        for (int kt = 0; kt < 3; ++kt) {
            f16x8 a0 = *(const f16x8*)&feat[(rb + ar) * FPAD + kt * 32 + kg * 8];
            f16x8 a1 = *(const f16x8*)&feat[(rb + 16 + ar) * FPAD + kt * 32 + kg * 8];
#pragma unroll
            for (int nt = 0; nt < 4; ++nt) {
                f16x8 bb = *(const f16x8*)&wt0[(nt * 16 + ar) * FPAD + kt * 32 + kg * 8];
                acc[0][nt] = __builtin_amdgcn_mfma_f32_16x16x32_f16(a0, bb, acc[0][nt], 0, 0, 0);
                acc[1][nt] = __builtin_amdgcn_mfma_f32_16x16x32_f16(a1, bb, acc[1][nt], 0, 0, 0);
            }
        }
#pragma unroll
        for (int mt = 0; mt < 2; ++mt)
#pragma unroll
            for (int nt = 0; nt < 4; ++nt)
#pragma unroll
                for (int ri = 0; ri < 4; ++ri) {
                    int row = rb + mt * 16 + kg * 4 + ri;
                    int col = nt * 16 + ar;
                    float v = fmaxf(acc[mt][nt][ri] + bias0[col], 0.0f);
                    h1[row * HPAD + col] = (_Float16)v;
                }
    }
    __syncthreads();

    // GEMM2: h1[256x64] x W1 -> h2 (reusing feat), relu
    _Float16* h2 = feat;
    {
        f32x4 acc[2][4] = {};
#pragma unroll
        for (int kt = 0; kt < 2; ++kt) {
            f16x8 a0 = *(const f16x8*)&h1[(rb + ar) * HPAD + kt * 32 + kg * 8];
            f16x8 a1 = *(const f16x8*)&h1[(rb + 16 + ar) * HPAD + kt * 32 + kg * 8];
#pragma unroll
            for (int nt = 0; nt < 4; ++nt) {
                f16x8 bb = *(const f16x8*)&wt1[(nt * 16 + ar) * HPAD + kt * 32 + kg * 8];
                acc[0][nt] = __builtin_amdgcn_mfma_f32_16x16x32_f16(a0, bb, acc[0][nt], 0, 0, 0);
                acc[1][nt] = __builtin_amdgcn_mfma_f32_16x16x32_f16(a1, bb, acc[1][nt], 0, 0, 0);
            }
        }
#pragma unroll
        for (int mt = 0; mt < 2; ++mt)
#pragma unroll
            for (int nt = 0; nt < 4; ++nt)
#pragma unroll
                for (int ri = 0; ri < 4; ++ri) {
                    int row = rb + mt * 16 + kg * 4 + ri;
                    int col = nt * 16 + ar;
                    float v = fmaxf(acc[mt][nt][ri] + bias1[col], 0.0f);
                    h2[row * HPAD + col] = (_Float16)v;
                }
    }
    __syncthreads();

    // GEMM3: h2[256x64] x W2 -> [256x128], relu + masked max-pool over k=32
    {
        f32x4 acc[2][8] = {};
#pragma unroll
        for (int kt = 0; kt < 2; ++kt) {
            f16x8 a0 = *(const f16x8*)&h2[(rb + ar) * HPAD + kt * 32 + kg * 8];
            f16x8 a1 = *(const f16x8*)&h2[(rb + 16 + ar) * HPAD + kt * 32 + kg * 8];
#pragma unroll
            for (int nt = 0; nt < 8; ++nt) {
                f16x8 bb = *(const f16x8*)&wt2[(nt * 16 + ar) * HPAD + kt * 32 + kg * 8];
                acc[0][nt] = __builtin_amdgcn_mfma_f32_16x16x32_f16(a0, bb, acc[0][nt], 0, 0, 0);
                acc[1][nt] = __builtin_amdgcn_mfma_f32_16x16x32_f16(a1, bb, acc[1][nt], 0, 0, 0);
            }
        }
        const int g = g0 + w;
#pragma unroll
        for (int nt = 0; nt < 8; ++nt) {
            int col = nt * 16 + ar;
            float bz = bias2[col];
            float bmax = 0.0f;   // h>=0 post-relu and self is always valid
#pragma unroll
            for (int mt = 0; mt < 2; ++mt)
#pragma unroll
                for (int ri = 0; ri < 4; ++ri) {
                    int row = rb + mt * 16 + kg * 4 + ri;
                    float v = fmaxf(acc[mt][nt][ri] + bz, 0.0f);
                    bmax = fmaxf(bmax, vld[row] ? v : 0.0f);
                }
            bmax = fmaxf(bmax, __shfl_xor(bmax, 16));
            bmax = fmaxf(bmax, __shfl_xor(bmax, 32));
            if (lane < 16) x1[(size_t)g * 128 + nt * 16 + lane] = bmax;
        }
    }
}

extern "C" void kernel_launch(void* const* d_in, const int* in_sizes, int n_in,
                              void* d_out, int out_size, void* d_ws, size_t ws_size,
                              hipStream_t stream) {
    const float* x   = (const float*)d_in[0];
    const float* pos = (const float*)d_in[1];
    const float* W0  = (const float*)d_in[2];
    const float* b0  = (const float*)d_in[3];
    const float* W1  = (const float*)d_in[4];
    const float* b1  = (const float*)d_in[5];
    const float* W2  = (const float*)d_in[6];
    const float* b2  = (const float*)d_in[7];
    float* x1    = (float*)d_out;
    float* pos_s = x1 + (size_t)NB * NM * 128;   // outputs concatenated: x1 then pos_s
    int* nbr = (int*)d_ws;                        // [NB*NM, NK] int32 = 2MB

    fps_kernel<<<NB, 256, 0, stream>>>(pos, pos_s);
    knn_kernel<<<(NB * NM) / GQ, 256, 0, stream>>>(pos, pos_s, nbr);
    mlp_kernel<<<(NB * NM) / TG, 512, 0, stream>>>(x, pos, W0, b0, W1, b1, W2, b2,
                                                   pos_s, nbr, x1);
}

// Round 12
// 12410.511 us; speedup vs baseline: 1.2093x; 1.2093x over previous
//
#include <hip/hip_runtime.h>
#include <hip/hip_bf16.h>
#include <hip/hip_fp16.h>

#define NB 8
#define NP 8192
#define NC 64
#define NM 2048
#define NK 32
#define RAD2 0.04f

typedef unsigned int u32;
typedef unsigned long long u64;
typedef _Float16 f16x8 __attribute__((ext_vector_type(8)));
typedef float f32x4 __attribute__((ext_vector_type(4)));

// exact reference arithmetic: ((dx*dx + dy*dy) + dz*dz), no FMA contraction
__device__ __forceinline__ float d2e(float ax, float ay, float az,
                                     float bx, float by, float bz) {
    float dx = __fsub_rn(ax, bx), dy = __fsub_rn(ay, by), dz = __fsub_rn(az, bz);
    return __fadd_rn(__fadd_rn(__fmul_rn(dx, dx), __fmul_rn(dy, dy)), __fmul_rn(dz, dz));
}

__device__ __forceinline__ int spread3(int v) {
    return (v & 1) | ((v & 2) << 2) | ((v & 4) << 4);
}

// one DPP combine level of u64 max (keys unique -> strict > is exact)
#define RED64(CTRL) do {                                                              \
    u32 hi_ = (u32)(k >> 32), lo_ = (u32)k;                                           \
    u32 h2_ = (u32)__builtin_amdgcn_update_dpp((int)hi_, (int)hi_, (CTRL), 0xF, 0xF, false); \
    u32 l2_ = (u32)__builtin_amdgcn_update_dpp((int)lo_, (int)lo_, (CTRL), 0xF, 0xF, false); \
    u64 o_ = ((u64)h2_ << 32) | l2_;                                                  \
    if (o_ > k) k = o_;                                                               \
} while (0)

// ---------------- Kernel 1: farthest point sampling (1 block per cloud) ----
// 256-thread setup, then ONE WAVE runs the loop barrier/atomic-free.
// vs r10: (a) SoA interleaved arrays (4B lane stride -> conflict-free),
// (b) cell metadata TRANSPOSED [c][lane] (conflict-free), u64 split u32x2,
// (c) all rescan control via __ballot (scalar branches), divergent-c safe
// because bank depends on lane only, (d) no register arrays -> no spill.
__global__ __launch_bounds__(256, 1) void fps_kernel(const float* __restrict__ pos,
                                                     float* __restrict__ pos_s) {
    __shared__ float lsx[NP], lsy[NP], lsz[NP];   // 96K, idx = j*64 + lane
    __shared__ u32 lmind[NP];                     // 32K
    __shared__ unsigned short lsid[NP];           // 16K
    __shared__ float cbbT[8][6][64];              // 12K: [cell][lo x,hi x,lo y,hi y,lo z,hi z][lane]
    __shared__ u32 cmhi[8][64];                   // 2K: cell max key hi
    __shared__ u32 cmlo[8][64];                   // 2K: cell max key lo
    u32* hist = (u32*)&cbbT[0][0][0];             // setup overlay (dead before phase C)
    u32* cursor = hist + 512;

    const int b = blockIdx.x;
    const int tid = threadIdx.x;
    const float* pb = pos + (size_t)b * (NP * 3);
    const float s0x = pb[0], s0y = pb[1], s0z = pb[2];   // uniform cached loads

    hist[tid] = 0; hist[tid + 256] = 0;
    __syncthreads();

    // ---- phase A: morton histogram (4 chunks x 8 contiguous pts) ----
    for (int ch = 0; ch < 4; ++ch) {
        float f[24];
        const float4* src = (const float4*)(pb + (size_t)(tid * 32 + ch * 8) * 3);
#pragma unroll
        for (int v = 0; v < 6; ++v) *(float4*)&f[v * 4] = src[v];
#pragma unroll
        for (int j = 0; j < 8; ++j) {
            int qx = min(7, max(0, (int)(f[3 * j] * 8.0f)));
            int qy = min(7, max(0, (int)(f[3 * j + 1] * 8.0f)));
            int qz = min(7, max(0, (int)(f[3 * j + 2] * 8.0f)));
            int key = (spread3(qx) << 2) | (spread3(qy) << 1) | spread3(qz);
            atomicAdd(&hist[key], 1);
        }
    }
    __syncthreads();
    // inclusive scan over 512 bins with 256 threads (2 bins/thread)
    for (int off = 1; off < 512; off <<= 1) {
        u32 a0 = (tid >= off) ? hist[tid - off] : 0;
        u32 a1 = hist[tid + 256 - off];
        __syncthreads();
        hist[tid] += a0; hist[tid + 256] += a1;
        __syncthreads();
    }
    cursor[tid] = (tid == 0) ? 0u : hist[tid - 1];
    cursor[tid + 256] = hist[tid + 255];
    __syncthreads();

    // ---- phase B: scatter into morton order (interleaved SoA) + mind init --
    for (int ch = 0; ch < 4; ++ch) {
        float f[24];
        const float4* src = (const float4*)(pb + (size_t)(tid * 32 + ch * 8) * 3);
#pragma unroll
        for (int v = 0; v < 6; ++v) *(float4*)&f[v * 4] = src[v];
#pragma unroll
        for (int j = 0; j < 8; ++j) {
            float x = f[3 * j], y = f[3 * j + 1], z = f[3 * j + 2];
            int qx = min(7, max(0, (int)(x * 8.0f)));
            int qy = min(7, max(0, (int)(y * 8.0f)));
            int qz = min(7, max(0, (int)(z * 8.0f)));
            int key = (spread3(qx) << 2) | (spread3(qy) << 1) | spread3(qz);
            int dst = (int)atomicAdd(&cursor[key], 1);
            int m = ((dst & 127) << 6) | (dst >> 7);   // j*64 + lane
            lsx[m] = x; lsy[m] = y; lsz[m] = z;
            lsid[m] = (unsigned short)(tid * 32 + ch * 8 + j);
            lmind[m] = __float_as_uint(d2e(x, y, z, s0x, s0y, s0z));
        }
    }
    __syncthreads();

    // ---- phase C: cell metadata (512 cells, 2/thread), overlays hist ----
#pragma unroll
    for (int half = 0; half < 2; ++half) {
        int cell = tid + half * 256;
        int L = cell >> 3, c = cell & 7;
        float lx = 1e30f, hx = -1e30f, ly = 1e30f, hy = -1e30f, lz = 1e30f, hz = -1e30f;
        u64 cm = 0;
        for (int i = 0; i < 16; ++i) {
            int m = ((c * 16 + i) << 6) | L;
            float x = lsx[m], y = lsy[m], z = lsz[m];
            u64 kk = ((u64)lmind[m] << 32)
                   | (((8191u - (u32)lsid[m]) << 13) | (u32)(L * 128 + c * 16 + i));
            cm = (kk > cm) ? kk : cm;
            lx = fminf(lx, x); hx = fmaxf(hx, x);
            ly = fminf(ly, y); hy = fmaxf(hy, y);
            lz = fminf(lz, z); hz = fmaxf(hz, z);
        }
        cbbT[c][0][L] = lx; cbbT[c][1][L] = hx;
        cbbT[c][2][L] = ly; cbbT[c][3][L] = hy;
        cbbT[c][4][L] = lz; cbbT[c][5][L] = hz;
        cmhi[c][L] = (u32)(cm >> 32); cmlo[c][L] = (u32)cm;
    }
    __syncthreads();

    float* outp = pos_s + (size_t)b * (NM * 3);
    if (tid == 0) { outp[0] = s0x; outp[1] = s0y; outp[2] = s0z; }
    if (tid >= 64) return;   // waves 1-3 done; wave 0 runs barrier-free

    const int lane = tid;
    float llox = 1e30f, lhix = -1e30f, lloy = 1e30f, lhiy = -1e30f;
    float lloz = 1e30f, lhiz = -1e30f;
    u64 lmax = 0;
#pragma unroll
    for (int c = 0; c < 8; ++c) {
        llox = fminf(llox, cbbT[c][0][lane]); lhix = fmaxf(lhix, cbbT[c][1][lane]);
        lloy = fminf(lloy, cbbT[c][2][lane]); lhiy = fmaxf(lhiy, cbbT[c][3][lane]);
        lloz = fminf(lloz, cbbT[c][4][lane]); lhiz = fmaxf(lhiz, cbbT[c][5][lane]);
        u64 cm = ((u64)cmhi[c][lane] << 32) | cmlo[c][lane];
        lmax = (cm > lmax) ? cm : lmax;
    }

    // ---- main loop: single wave, no barriers, no atomics ----
    for (int t = 1; t < NM; ++t) {
        u64 k = lmax;
        RED64(0x111); RED64(0x112); RED64(0x114);
        RED64(0x118); RED64(0x142); RED64(0x143);
        const u32 glo = (u32)__builtin_amdgcn_readlane((int)(u32)k, 63);
        const int srt = (int)(glo & 0x1FFFu);
        const int m = ((srt & 127) << 6) | (srt >> 7);
        const float sx = lsx[m], sy = lsy[m], sz = lsz[m];   // broadcast reads
        if (lane == 0) { outp[3 * t] = sx; outp[3 * t + 1] = sy; outp[3 * t + 2] = sz; }
        // lane-level certified skip (register bbox over my 128 pts)
        float gx = fmaxf(fmaxf(llox - sx, sx - lhix), 0.0f);
        float gy = fmaxf(fmaxf(lloy - sy, sy - lhiy), 0.0f);
        float gz = fmaxf(fmaxf(lloz - sz, sz - lhiz), 0.0f);
        float bnd = gx * gx + gy * gy + gz * gz;
        bool lg = (bnd * 0.999999f < __uint_as_float((u32)(lmax >> 32)));
        if (__ballot(lg) != 0ull) {          // wave-uniform branch
            // per-cell certified gates (conflict-free transposed meta)
            u32 gmask = 0;
#pragma unroll
            for (int c = 0; c < 8; ++c) {
                float cgx = fmaxf(fmaxf(cbbT[c][0][lane] - sx, sx - cbbT[c][1][lane]), 0.0f);
                float cgy = fmaxf(fmaxf(cbbT[c][2][lane] - sy, sy - cbbT[c][3][lane]), 0.0f);
                float cgz = fmaxf(fmaxf(cbbT[c][4][lane] - sz, sz - cbbT[c][5][lane]), 0.0f);
                float cbnd = cgx * cgx + cgy * cgy + cgz * cgz;
                bool g = lg && (cbnd * 0.999999f < __uint_as_float(cmhi[c][lane]));
                gmask |= g ? (1u << c) : 0u;
            }
            u32 msk = gmask;
            while (__ballot(msk != 0u) != 0ull) {   // wave-uniform loop
                if (msk) {
                    int c = (int)__builtin_ctz(msk);
                    msk &= msk - 1;
                    u64 cm = 0;
#pragma unroll
                    for (int i = 0; i < 16; ++i) {
                        int m2 = ((c * 16 + i) << 6) | lane;
                        float d = d2e(lsx[m2], lsy[m2], lsz[m2], sx, sy, sz);
                        u32 nmi = min(lmind[m2], __float_as_uint(d));
                        lmind[m2] = nmi;
                        u64 kk = ((u64)nmi << 32)
                               | (((8191u - (u32)lsid[m2]) << 13)
                                  | (u32)(lane * 128 + c * 16 + i));
                        cm = (kk > cm) ? kk : cm;
                    }
                    cmhi[c][lane] = (u32)(cm >> 32);
                    cmlo[c][lane] = (u32)cm;
                }
            }
            if (lg) {   // recompute lane max over my 8 cells
                u64 nl = 0;
#pragma unroll
                for (int c = 0; c < 8; ++c) {
                    u64 cm = ((u64)cmhi[c][lane] << 32) | cmlo[c][lane];
                    nl = (cm > nl) ? cm : nl;
                }
                lmax = nl;
            }
        }
    }
}

// ---------------- Kernel 2: radius-limited 32-NN (8 queries per block) -----
#define GQ 8
#define CAP 768
__global__ __launch_bounds__(256, 1) void knn_kernel(const float* __restrict__ pos,
                                                     const float* __restrict__ pos_s,
                                                     int* __restrict__ nbr) {
    __shared__ u64 keys[GQ][CAP];
    __shared__ int cnt[GQ];
    const int qbase = blockIdx.x * GQ;
    const int b = qbase >> 11;
    const int tid = threadIdx.x;
    if (tid < GQ) cnt[tid] = 0;
    for (int i = tid; i < GQ * NK; i += 256) nbr[qbase * NK + i] = -1;

    float qx[GQ], qy[GQ], qz[GQ];
#pragma unroll
    for (int q = 0; q < GQ; ++q) {
        qx[q] = pos_s[(qbase + q) * 3];
        qy[q] = pos_s[(qbase + q) * 3 + 1];
        qz[q] = pos_s[(qbase + q) * 3 + 2];
    }
    __syncthreads();

    const float* pb = pos + (size_t)b * (NP * 3);
    for (int i = 0; i < NP / 256; ++i) {
        int p = tid + (i << 8);
        float x = pb[3 * p], y = pb[3 * p + 1], z = pb[3 * p + 2];
#pragma unroll
        for (int q = 0; q < GQ; ++q) {
            float d = d2e(x, y, z, qx[q], qy[q], qz[q]);
            if (d <= RAD2) {
                int slot = atomicAdd(&cnt[q], 1);
                if (slot < CAP) keys[q][slot] = ((u64)__float_as_uint(d) << 32) | (u32)p;
            }
        }
    }
    __syncthreads();

    // exact rank selection: keys are unique (idx in low bits) -> stable top-k
    for (int q = 0; q < GQ; ++q) {
        int c = min(cnt[q], CAP);
        for (int j = tid; j < c; j += 256) {
            u64 key = keys[q][j];
            int rank = 0;
            for (int t2 = 0; t2 < c; ++t2) rank += (keys[q][t2] < key) ? 1 : 0;
            if (rank < NK) nbr[(qbase + q) * NK + rank] = (int)(u32)(key & 0xFFFFFFFFull);
        }
    }
}

// ---------------- Kernel 3: gather + MLP (fp16 MFMA) + masked max-pool -----
#define FPAD 104
#define HPAD 72
#define TG 8
__global__ __launch_bounds__(512, 1) void mlp_kernel(
    const float* __restrict__ x, const float* __restrict__ pos,
    const float* __restrict__ W0, const float* __restrict__ b0,
    const float* __restrict__ W1, const float* __restrict__ b1,
    const float* __restrict__ W2, const float* __restrict__ b2,
    const float* __restrict__ pos_s, const int* __restrict__ nbr,
    float* __restrict__ x1) {
    __shared__ _Float16 feat[256 * FPAD];   // reused as h2[256][HPAD] after GEMM1
    __shared__ _Float16 h1[256 * HPAD];
    __shared__ _Float16 wt0[64 * FPAD];
    __shared__ _Float16 wt1[64 * HPAD];
    __shared__ _Float16 wt2[128 * HPAD];
    __shared__ float bias0[64], bias1[64], bias2[128];
    __shared__ int vld[256];

    const int tid = threadIdx.x;
    const int g0 = blockIdx.x * TG;
    const int b = g0 >> 11;

    // stage weights transposed: wt[c][j] = W[j][c], zero-padded in K
    for (int idx = tid; idx < 64 * FPAD; idx += 512) {
        int c2 = idx / FPAD, j = idx - c2 * FPAD;
        wt0[idx] = (_Float16)((j < 67) ? W0[j * 64 + c2] : 0.0f);
    }
    for (int idx = tid; idx < 64 * HPAD; idx += 512) {
        int c2 = idx / HPAD, j = idx - c2 * HPAD;
        wt1[idx] = (_Float16)((j < 64) ? W1[j * 64 + c2] : 0.0f);
    }
    for (int idx = tid; idx < 128 * HPAD; idx += 512) {
        int c2 = idx / HPAD, j = idx - c2 * HPAD;
        wt2[idx] = (_Float16)((j < 64) ? W2[j * 128 + c2] : 0.0f);
    }
    if (tid < 64) { bias0[tid] = b0[tid]; bias1[tid] = b1[tid]; }
    else if (tid < 192) bias2[tid - 64] = b2[tid - 64];

    // gather features: 2 threads per row, rows = (group, k)
    {
        int r = tid >> 1, half = tid & 1;
        int g = g0 + (r >> 5), k = r & 31;
        int nid = nbr[g * NK + k];
        int nid2 = nid < 0 ? 0 : nid;
        const float* xr = x + ((size_t)b * NP + nid2) * NC + half * 32;
        _Float16* dst = &feat[r * FPAD + half * 32];
#pragma unroll
        for (int i = 0; i < 8; ++i) {
            float4 v = *(const float4*)(xr + i * 4);
            dst[i * 4 + 0] = (_Float16)v.x; dst[i * 4 + 1] = (_Float16)v.y;
            dst[i * 4 + 2] = (_Float16)v.z; dst[i * 4 + 3] = (_Float16)v.w;
        }
        if (half) {
            const float* pj = pos + ((size_t)b * NP + nid2) * 3;
            const float* ps = pos_s + (size_t)g * 3;
            feat[r * FPAD + 64] = (_Float16)(pj[0] - ps[0]);
            feat[r * FPAD + 65] = (_Float16)(pj[1] - ps[1]);
            feat[r * FPAD + 66] = (_Float16)(pj[2] - ps[2]);
#pragma unroll
            for (int j = 67; j < 96; ++j) feat[r * FPAD + j] = (_Float16)0.0f;
        } else {
            vld[r] = (nid >= 0) ? 1 : 0;
        }
    }
    __syncthreads();

    const int lane = tid & 63, w = tid >> 6;
    const int rb = w * 32;          // this wave owns one (b,m) group = 32 rows
    const int ar = lane & 15;
    const int kg = lane >> 4;

    // GEMM1: feat[256x96] x W0 -> h1[256x64], relu
    {
        f32x4 acc[2][4] = {};
#pragma unroll
        for (int kt = 0; kt < 3; ++kt) {
            f16x8 a0 = *(const f16x8*)&feat[(rb + ar) * FPAD + kt * 32 + kg * 8];
            f16x8 a1 = *(const f16x8*)&feat[(rb + 16 + ar) * FPAD + kt * 32 + kg * 8];
#pragma unroll
            for (int nt = 0; nt < 4; ++nt) {
                f16x8 bb = *(const f16x8*)&wt0[(nt * 16 + ar) * FPAD + kt * 32 + kg * 8];
                acc[0][nt] = __builtin_amdgcn_mfma_f32_16x16x32_f16(a0, bb, acc[0][nt], 0, 0, 0);
                acc[1][nt] = __builtin_amdgcn_mfma_f32_16x16x32_f16(a1, bb, acc[1][nt], 0, 0, 0);
            }
        }
#pragma unroll
        for (int mt = 0; mt < 2; ++mt)
#pragma unroll
            for (int nt = 0; nt < 4; ++nt)
#pragma unroll
                for (int ri = 0; ri < 4; ++ri) {
                    int row = rb + mt * 16 + kg * 4 + ri;
                    int col = nt * 16 + ar;
                    float v = fmaxf(acc[mt][nt][ri] + bias0[col], 0.0f);
                    h1[row * HPAD + col] = (_Float16)v;
                }
    }
    __syncthreads();

    // GEMM2: h1[256x64] x W1 -> h2 (reusing feat), relu
    _Float16* h2 = feat;
    {
        f32x4 acc[2][4] = {};
#pragma unroll
        for (int kt = 0; kt < 2; ++kt) {
            f16x8 a0 = *(const f16x8*)&h1[(rb + ar) * HPAD + kt * 32 + kg * 8];
            f16x8 a1 = *(const f16x8*)&h1[(rb + 16 + ar) * HPAD + kt * 32 + kg * 8];
#pragma unroll
            for (int nt = 0; nt < 4; ++nt) {
                f16x8 bb = *(const f16x8*)&wt1[(nt * 16 + ar) * HPAD + kt * 32 + kg * 8];
                acc[0][nt] = __builtin_amdgcn_mfma_f32_16x16x32_f16(a0, bb, acc[0][nt], 0, 0, 0);
                acc[1][nt] = __builtin_amdgcn_mfma_f32_16x16x32_f16(a1, bb, acc[1][nt], 0, 0, 0);
            }
        }
#pragma unroll
        for (int mt = 0; mt < 2; ++mt)
#pragma unroll
            for (int nt = 0; nt < 4; ++nt)
#pragma unroll
                for (int ri = 0; ri < 4; ++ri) {
                    int row = rb + mt * 16 + kg * 4 + ri;
                    int col = nt * 16 + ar;
                    float v = fmaxf(acc[mt][nt][ri] + bias1[col], 0.0f);
                    h2[row * HPAD + col] = (_Float16)v;
                }
    }
    __syncthreads();

    // GEMM3: h2[256x64] x W2 -> [256x128], relu + masked max-pool over k=32
    {
        f32x4 acc[2][8] = {};
#pragma unroll
        for (int kt = 0; kt < 2; ++kt) {
            f16x8 a0 = *(const f16x8*)&h2[(rb + ar) * HPAD + kt * 32 + kg * 8];
            f16x8 a1 = *(const f16x8*)&h2[(rb + 16 + ar) * HPAD + kt * 32 + kg * 8];
#pragma unroll
            for (int nt = 0; nt < 8; ++nt) {
                f16x8 bb = *(const f16x8*)&wt2[(nt * 16 + ar) * HPAD + kt * 32 + kg * 8];
                acc[0][nt] = __builtin_amdgcn_mfma_f32_16x16x32_f16(a0, bb, acc[0][nt], 0, 0, 0);
                acc[1][nt] = __builtin_amdgcn_mfma_f32_16x16x32_f16(a1, bb, acc[1][nt], 0, 0, 0);
            }
        }
        const int g = g0 + w;
#pragma unroll
        for (int nt = 0; nt < 8; ++nt) {
            int col = nt * 16 + ar;
            float bz = bias2[col];
            float bmax = 0.0f;   // h>=0 post-relu and self is always valid
#pragma unroll
            for (int mt = 0; mt < 2; ++mt)
#pragma unroll
                for (int ri = 0; ri < 4; ++ri) {
                    int row = rb + mt * 16 + kg * 4 + ri;
                    float v = fmaxf(acc[mt][nt][ri] + bz, 0.0f);
                    bmax = fmaxf(bmax, vld[row] ? v : 0.0f);
                }
            bmax = fmaxf(bmax, __shfl_xor(bmax, 16));
            bmax = fmaxf(bmax, __shfl_xor(bmax, 32));
            if (lane < 16) x1[(size_t)g * 128 + nt * 16 + lane] = bmax;
        }
    }
}

extern "C" void kernel_launch(void* const* d_in, const int* in_sizes, int n_in,
                              void* d_out, int out_size, void* d_ws, size_t ws_size,
                              hipStream_t stream) {
    const float* x   = (const float*)d_in[0];
    const float* pos = (const float*)d_in[1];
    const float* W0  = (const float*)d_in[2];
    const float* b0  = (const float*)d_in[3];
    const float* W1  = (const float*)d_in[4];
    const float* b1  = (const float*)d_in[5];
    const float* W2  = (const float*)d_in[6];
    const float* b2  = (const float*)d_in[7];
    float* x1    = (float*)d_out;
    float* pos_s = x1 + (size_t)NB * NM * 128;   // outputs concatenated: x1 then pos_s
    int* nbr = (int*)d_ws;                        // [NB*NM, NK] int32 = 2MB

    fps_kernel<<<NB, 256, 0, stream>>>(pos, pos_s);
    knn_kernel<<<(NB * NM) / GQ, 256, 0, stream>>>(pos, pos_s, nbr);
    mlp_kernel<<<(NB * NM) / TG, 512, 0, stream>>>(x, pos, W0, b0, W1, b1, W2, b2,
                                                   pos_s, nbr, x1);
}

// Round 13
// 1678.596 us; speedup vs baseline: 8.9412x; 7.3934x over previous
//
#include <hip/hip_runtime.h>
#include <hip/hip_bf16.h>
#include <hip/hip_fp16.h>

#define NB 8
#define NP 8192
#define NC 64
#define NM 2048
#define NK 32
#define RAD2 0.04f

typedef unsigned int u32;
typedef unsigned long long u64;
typedef _Float16 f16x8 __attribute__((ext_vector_type(8)));
typedef float f32x4 __attribute__((ext_vector_type(4)));

// exact reference arithmetic: ((dx*dx + dy*dy) + dz*dz), no FMA contraction
__device__ __forceinline__ float d2e(float ax, float ay, float az,
                                     float bx, float by, float bz) {
    float dx = __fsub_rn(ax, bx), dy = __fsub_rn(ay, by), dz = __fsub_rn(az, bz);
    return __fadd_rn(__fadd_rn(__fmul_rn(dx, dx), __fmul_rn(dy, dy)), __fmul_rn(dz, dz));
}

__device__ __forceinline__ int spread3(int v) {
    return (v & 1) | ((v & 2) << 2) | ((v & 4) << 4);
}

// one DPP combine level of u64 max (keys unique -> strict > is exact)
#define RED64(CTRL) do {                                                              \
    u32 hi_ = (u32)(k >> 32), lo_ = (u32)k;                                           \
    u32 h2_ = (u32)__builtin_amdgcn_update_dpp((int)hi_, (int)hi_, (CTRL), 0xF, 0xF, false); \
    u32 l2_ = (u32)__builtin_amdgcn_update_dpp((int)lo_, (int)lo_, (CTRL), 0xF, 0xF, false); \
    u64 o_ = ((u64)h2_ << 32) | l2_;                                                  \
    if (o_ > k) k = o_;                                                               \
} while (0)

// ---------------- Kernel 1: farthest point sampling (1 block per cloud) ----
// 1024 threads x 8 pts. Morton-sorted + certified skip + wave-key caching.
// (Best-measured structure of the session: fps ~1330 us.)
#define FPT 8
__global__ __launch_bounds__(1024, 1) void fps_kernel(const float* __restrict__ pos,
                                                      float* __restrict__ pos_s) {
    __shared__ float ssx[NP], ssy[NP], ssz[NP];
    __shared__ u32 ssid[NP];
    __shared__ u32 hist[512], cursor[512];
    __shared__ u64 gkey[3];
    __shared__ u32 pos0srt;

    const int b = blockIdx.x;
    const int tid = threadIdx.x;
    const int lane = tid & 63;
    const float* pb = pos + (size_t)b * (NP * 3);

    // ---- phase A: load my 8 points (24 contiguous floats), morton keys ----
    float ax[FPT], ay[FPT], az[FPT];
    int key[FPT];
    {
        float f[24];
        const float4* src = (const float4*)(pb + tid * 24);
#pragma unroll
        for (int v = 0; v < 6; ++v) *(float4*)&f[v * 4] = src[v];
#pragma unroll
        for (int j = 0; j < FPT; ++j) {
            ax[j] = f[3 * j]; ay[j] = f[3 * j + 1]; az[j] = f[3 * j + 2];
            int qx = min(7, max(0, (int)(ax[j] * 8.0f)));
            int qy = min(7, max(0, (int)(ay[j] * 8.0f)));
            int qz = min(7, max(0, (int)(az[j] * 8.0f)));
            key[j] = (spread3(qx) << 2) | (spread3(qy) << 1) | spread3(qz);
        }
    }
    if (tid < 512) hist[tid] = 0;
    __syncthreads();
#pragma unroll
    for (int j = 0; j < FPT; ++j) atomicAdd(&hist[key[j]], 1);
    __syncthreads();
    // inclusive scan over 512 bins (Hillis-Steele)
    for (int off = 1; off < 512; off <<= 1) {
        u32 v = 0;
        if (tid < 512 && tid >= off) v = hist[tid - off];
        __syncthreads();
        if (tid < 512) hist[tid] += v;
        __syncthreads();
    }
    if (tid < 512) cursor[tid] = (tid == 0) ? 0u : hist[tid - 1];
    if (tid == 0) { gkey[0] = 0; gkey[1] = 0; gkey[2] = 0; }
    __syncthreads();
    // ---- phase B: scatter into morton order ----
#pragma unroll
    for (int j = 0; j < FPT; ++j) {
        int dst = (int)atomicAdd(&cursor[key[j]], 1);
        ssx[dst] = ax[j]; ssy[dst] = ay[j]; ssz[dst] = az[j];
        u32 orig = tid * FPT + j;
        ssid[dst] = orig;
        if (orig == 0) pos0srt = (u32)dst;
    }
    __syncthreads();

    // ---- phase C: register-load my sorted range, bbox, init vs point 0 ----
    const int base = tid * FPT;
    const u32 p0 = pos0srt;
    const float s0x = ssx[p0], s0y = ssy[p0], s0z = ssz[p0];
    float px[FPT], py[FPT], pz[FPT];
    u64 mkey[FPT];
    float lox, hix, loy, hiy, loz, hiz;
#pragma unroll
    for (int j = 0; j < FPT; ++j) {
        px[j] = ssx[base + j]; py[j] = ssy[base + j]; pz[j] = ssz[base + j];
        u32 sid = ssid[base + j];
        float d = d2e(px[j], py[j], pz[j], s0x, s0y, s0z);
        u32 lo = ((8191u - sid) << 13) | (u32)(base + j);
        mkey[j] = ((u64)__float_as_uint(d) << 32) | lo;
        if (j == 0) {
            lox = hix = px[0]; loy = hiy = py[0]; loz = hiz = pz[0];
        } else {
            lox = fminf(lox, px[j]); hix = fmaxf(hix, px[j]);
            loy = fminf(loy, py[j]); hiy = fmaxf(hiy, py[j]);
            loz = fminf(loz, pz[j]); hiz = fmaxf(hiz, pz[j]);
        }
    }
    float* outp = pos_s + (size_t)b * (NM * 3);
    if (tid == 0) { outp[0] = s0x; outp[1] = s0y; outp[2] = s0z; }
    u64 ck = mkey[0];
#pragma unroll
    for (int j = 1; j < FPT; ++j) ck = (mkey[j] > ck) ? mkey[j] : ck;

    // ---- main loop: one barrier per iteration; reduce only if wave changed --
    bool upd = true;
    u64 wkey = 0;
    int slot = 1, prv = 0;
    for (int t = 1; t < NM; ++t) {
        if (__ballot(upd)) {
            u64 k = ck;
            RED64(0x111);  // row_shr:1
            RED64(0x112);  // row_shr:2
            RED64(0x114);  // row_shr:4
            RED64(0x118);  // row_shr:8
            RED64(0x142);  // row_bcast:15
            RED64(0x143);  // row_bcast:31
            wkey = k;
        }
        if (lane == 63) atomicMax(&gkey[slot], wkey);
        __syncthreads();
        u64 gk = gkey[slot];
        if (tid == 0) gkey[prv] = 0;   // 3-slot rotation: race-free reset
        const int srt = (int)(gk & 0x1FFFu);
        const float sx = ssx[srt], sy = ssy[srt], sz = ssz[srt];
        if (tid == 0) { outp[3 * t] = sx; outp[3 * t + 1] = sy; outp[3 * t + 2] = sz; }
        // certified skip: minDist^2(bbox,s)*(1-1e-6) >= max mind in cell
        float gx = fmaxf(fmaxf(__fsub_rn(lox, sx), __fsub_rn(sx, hix)), 0.0f);
        float gy = fmaxf(fmaxf(__fsub_rn(loy, sy), __fsub_rn(sy, hiy)), 0.0f);
        float gz = fmaxf(fmaxf(__fsub_rn(loz, sz), __fsub_rn(sz, hiz)), 0.0f);
        float bnd = gx * gx + gy * gy + gz * gz;
        float cvf = __uint_as_float((u32)(ck >> 32));
        upd = (bnd * 0.999999f < cvf);
        if (upd) {
            u64 nk = 0;
#pragma unroll
            for (int j = 0; j < FPT; ++j) {
                float d = d2e(px[j], py[j], pz[j], sx, sy, sz);
                u32 hi = min((u32)(mkey[j] >> 32), __float_as_uint(d));
                u64 nm = ((u64)hi << 32) | (u32)mkey[j];
                mkey[j] = nm;
                nk = (j == 0) ? nm : ((nm > nk) ? nm : nk);
            }
            ck = nk;
        }
        prv = slot; slot = (slot == 2) ? 0 : slot + 1;
    }
}

// ---------------- Kernel 2: radius-limited 32-NN (8 queries per block) -----
#define GQ 8
#define CAP 768
__global__ __launch_bounds__(256, 1) void knn_kernel(const float* __restrict__ pos,
                                                     const float* __restrict__ pos_s,
                                                     int* __restrict__ nbr) {
    __shared__ u64 keys[GQ][CAP];
    __shared__ int cnt[GQ];
    const int qbase = blockIdx.x * GQ;
    const int b = qbase >> 11;
    const int tid = threadIdx.x;
    if (tid < GQ) cnt[tid] = 0;
    for (int i = tid; i < GQ * NK; i += 256) nbr[qbase * NK + i] = -1;

    float qx[GQ], qy[GQ], qz[GQ];
#pragma unroll
    for (int q = 0; q < GQ; ++q) {
        qx[q] = pos_s[(qbase + q) * 3];
        qy[q] = pos_s[(qbase + q) * 3 + 1];
        qz[q] = pos_s[(qbase + q) * 3 + 2];
    }
    __syncthreads();

    const float* pb = pos + (size_t)b * (NP * 3);
    for (int i = 0; i < NP / 256; ++i) {
        int p = tid + (i << 8);
        float x = pb[3 * p], y = pb[3 * p + 1], z = pb[3 * p + 2];
#pragma unroll
        for (int q = 0; q < GQ; ++q) {
            float d = d2e(x, y, z, qx[q], qy[q], qz[q]);
            if (d <= RAD2) {
                int slot = atomicAdd(&cnt[q], 1);
                if (slot < CAP) keys[q][slot] = ((u64)__float_as_uint(d) << 32) | (u32)p;
            }
        }
    }
    __syncthreads();

    // exact rank selection: keys are unique (idx in low bits) -> stable top-k
    for (int q = 0; q < GQ; ++q) {
        int c = min(cnt[q], CAP);
        for (int j = tid; j < c; j += 256) {
            u64 key = keys[q][j];
            int rank = 0;
            for (int t2 = 0; t2 < c; ++t2) rank += (keys[q][t2] < key) ? 1 : 0;
            if (rank < NK) nbr[(qbase + q) * NK + rank] = (int)(u32)(key & 0xFFFFFFFFull);
        }
    }
}

// ---------------- Kernel 3: gather + MLP (fp16 MFMA) + masked max-pool -----
#define FPAD 104
#define HPAD 72
#define TG 8
__global__ __launch_bounds__(512, 1) void mlp_kernel(
    const float* __restrict__ x, const float* __restrict__ pos,
    const float* __restrict__ W0, const float* __restrict__ b0,
    const float* __restrict__ W1, const float* __restrict__ b1,
    const float* __restrict__ W2, const float* __restrict__ b2,
    const float* __restrict__ pos_s, const int* __restrict__ nbr,
    float* __restrict__ x1) {
    __shared__ _Float16 feat[256 * FPAD];   // reused as h2[256][HPAD] after GEMM1
    __shared__ _Float16 h1[256 * HPAD];
    __shared__ _Float16 wt0[64 * FPAD];
    __shared__ _Float16 wt1[64 * HPAD];
    __shared__ _Float16 wt2[128 * HPAD];
    __shared__ float bias0[64], bias1[64], bias2[128];
    __shared__ int vld[256];

    const int tid = threadIdx.x;
    const int g0 = blockIdx.x * TG;
    const int b = g0 >> 11;

    // stage weights transposed: wt[c][j] = W[j][c], zero-padded in K
    for (int idx = tid; idx < 64 * FPAD; idx += 512) {
        int c2 = idx / FPAD, j = idx - c2 * FPAD;
        wt0[idx] = (_Float16)((j < 67) ? W0[j * 64 + c2] : 0.0f);
    }
    for (int idx = tid; idx < 64 * HPAD; idx += 512) {
        int c2 = idx / HPAD, j = idx - c2 * HPAD;
        wt1[idx] = (_Float16)((j < 64) ? W1[j * 64 + c2] : 0.0f);
    }
    for (int idx = tid; idx < 128 * HPAD; idx += 512) {
        int c2 = idx / HPAD, j = idx - c2 * HPAD;
        wt2[idx] = (_Float16)((j < 64) ? W2[j * 128 + c2] : 0.0f);
    }
    if (tid < 64) { bias0[tid] = b0[tid]; bias1[tid] = b1[tid]; }
    else if (tid < 192) bias2[tid - 64] = b2[tid - 64];

    // gather features: 2 threads per row, rows = (group, k)
    {
        int r = tid >> 1, half = tid & 1;
        int g = g0 + (r >> 5), k = r & 31;
        int nid = nbr[g * NK + k];
        int nid2 = nid < 0 ? 0 : nid;
        const float* xr = x + ((size_t)b * NP + nid2) * NC + half * 32;
        _Float16* dst = &feat[r * FPAD + half * 32];
#pragma unroll
        for (int i = 0; i < 8; ++i) {
            float4 v = *(const float4*)(xr + i * 4);
            dst[i * 4 + 0] = (_Float16)v.x; dst[i * 4 + 1] = (_Float16)v.y;
            dst[i * 4 + 2] = (_Float16)v.z; dst[i * 4 + 3] = (_Float16)v.w;
        }
        if (half) {
            const float* pj = pos + ((size_t)b * NP + nid2) * 3;
            const float* ps = pos_s + (size_t)g * 3;
            feat[r * FPAD + 64] = (_Float16)(pj[0] - ps[0]);
            feat[r * FPAD + 65] = (_Float16)(pj[1] - ps[1]);
            feat[r * FPAD + 66] = (_Float16)(pj[2] - ps[2]);
#pragma unroll
            for (int j = 67; j < 96; ++j) feat[r * FPAD + j] = (_Float16)0.0f;
        } else {
            vld[r] = (nid >= 0) ? 1 : 0;
        }
    }
    __syncthreads();

    const int lane = tid & 63, w = tid >> 6;
    const int rb = w * 32;          // this wave owns one (b,m) group = 32 rows
    const int ar = lane & 15;
    const int kg = lane >> 4;

    // GEMM1: feat[256x96] x W0 -> h1[256x64], relu
    {
        f32x4 acc[2][4] = {};
#pragma unroll
        for (int kt = 0; kt < 3; ++kt) {
            f16x8 a0 = *(const f16x8*)&feat[(rb + ar) * FPAD + kt * 32 + kg * 8];
            f16x8 a1 = *(const f16x8*)&feat[(rb + 16 + ar) * FPAD + kt * 32 + kg * 8];
#pragma unroll
            for (int nt = 0; nt < 4; ++nt) {
                f16x8 bb = *(const f16x8*)&wt0[(nt * 16 + ar) * FPAD + kt * 32 + kg * 8];
                acc[0][nt] = __builtin_amdgcn_mfma_f32_16x16x32_f16(a0, bb, acc[0][nt], 0, 0, 0);
                acc[1][nt] = __builtin_amdgcn_mfma_f32_16x16x32_f16(a1, bb, acc[1][nt], 0, 0, 0);
            }
        }
#pragma unroll
        for (int mt = 0; mt < 2; ++mt)
#pragma unroll
            for (int nt = 0; nt < 4; ++nt)
#pragma unroll
                for (int ri = 0; ri < 4; ++ri) {
                    int row = rb + mt * 16 + kg * 4 + ri;
                    int col = nt * 16 + ar;
                    float v = fmaxf(acc[mt][nt][ri] + bias0[col], 0.0f);
                    h1[row * HPAD + col] = (_Float16)v;
                }
    }
    __syncthreads();

    // GEMM2: h1[256x64] x W1 -> h2 (reusing feat), relu
    _Float16* h2 = feat;
    {
        f32x4 acc[2][4] = {};
#pragma unroll
        for (int kt = 0; kt < 2; ++kt) {
            f16x8 a0 = *(const f16x8*)&h1[(rb + ar) * HPAD + kt * 32 + kg * 8];
            f16x8 a1 = *(const f16x8*)&h1[(rb + 16 + ar) * HPAD + kt * 32 + kg * 8];
#pragma unroll
            for (int nt = 0; nt < 4; ++nt) {
                f16x8 bb = *(const f16x8*)&wt1[(nt * 16 + ar) * HPAD + kt * 32 + kg * 8];
                acc[0][nt] = __builtin_amdgcn_mfma_f32_16x16x32_f16(a0, bb, acc[0][nt], 0, 0, 0);
                acc[1][nt] = __builtin_amdgcn_mfma_f32_16x16x32_f16(a1, bb, acc[1][nt], 0, 0, 0);
            }
        }
#pragma unroll
        for (int mt = 0; mt < 2; ++mt)
#pragma unroll
            for (int nt = 0; nt < 4; ++nt)
#pragma unroll
                for (int ri = 0; ri < 4; ++ri) {
                    int row = rb + mt * 16 + kg * 4 + ri;
                    int col = nt * 16 + ar;
                    float v = fmaxf(acc[mt][nt][ri] + bias1[col], 0.0f);
                    h2[row * HPAD + col] = (_Float16)v;
                }
    }
    __syncthreads();

    // GEMM3: h2[256x64] x W2 -> [256x128], relu + masked max-pool over k=32
    {
        f32x4 acc[2][8] = {};
#pragma unroll
        for (int kt = 0; kt < 2; ++kt) {
            f16x8 a0 = *(const f16x8*)&h2[(rb + ar) * HPAD + kt * 32 + kg * 8];
            f16x8 a1 = *(const f16x8*)&h2[(rb + 16 + ar) * HPAD + kt * 32 + kg * 8];
#pragma unroll
            for (int nt = 0; nt < 8; ++nt) {
                f16x8 bb = *(const f16x8*)&wt2[(nt * 16 + ar) * HPAD + kt * 32 + kg * 8];
                acc[0][nt] = __builtin_amdgcn_mfma_f32_16x16x32_f16(a0, bb, acc[0][nt], 0, 0, 0);
                acc[1][nt] = __builtin_amdgcn_mfma_f32_16x16x32_f16(a1, bb, acc[1][nt], 0, 0, 0);
            }
        }
        const int g = g0 + w;
#pragma unroll
        for (int nt = 0; nt < 8; ++nt) {
            int col = nt * 16 + ar;
            float bz = bias2[col];
            float bmax = 0.0f;   // h>=0 post-relu and self is always valid
#pragma unroll
            for (int mt = 0; mt < 2; ++mt)
#pragma unroll
                for (int ri = 0; ri < 4; ++ri) {
                    int row = rb + mt * 16 + kg * 4 + ri;
                    float v = fmaxf(acc[mt][nt][ri] + bz, 0.0f);
                    bmax = fmaxf(bmax, vld[row] ? v : 0.0f);
                }
            bmax = fmaxf(bmax, __shfl_xor(bmax, 16));
            bmax = fmaxf(bmax, __shfl_xor(bmax, 32));
            if (lane < 16) x1[(size_t)g * 128 + nt * 16 + lane] = bmax;
        }
    }
}

extern "C" void kernel_launch(void* const* d_in, const int* in_sizes, int n_in,
                              void* d_out, int out_size, void* d_ws, size_t ws_size,
                              hipStream_t stream) {
    const float* x   = (const float*)d_in[0];
    const float* pos = (const float*)d_in[1];
    const float* W0  = (const float*)d_in[2];
    const float* b0  = (const float*)d_in[3];
    const float* W1  = (const float*)d_in[4];
    const float* b1  = (const float*)d_in[5];
    const float* W2  = (const float*)d_in[6];
    const float* b2  = (const float*)d_in[7];
    float* x1    = (float*)d_out;
    float* pos_s = x1 + (size_t)NB * NM * 128;   // outputs concatenated: x1 then pos_s
    int* nbr = (int*)d_ws;                        // [NB*NM, NK] int32 = 2MB

    fps_kernel<<<NB, 1024, 0, stream>>>(pos, pos_s);
    knn_kernel<<<(NB * NM) / GQ, 256, 0, stream>>>(pos, pos_s, nbr);
    mlp_kernel<<<(NB * NM) / TG, 512, 0, stream>>>(x, pos, W0, b0, W1, b1, W2, b2,
                                                   pos_s, nbr, x1);
}